// Round 1
// baseline (529.991 us; speedup 1.0000x reference)
//
#include <hip/hip_runtime.h>

// TRF aligner: out[d, t] = sum over seq with s=sourceIdx[seq], 0 <= t-s < N_WIN
// of TRFs[seq, t-s, d]. Gather formulation (no atomics): sourceIdx is sorted,
// so each t-tile binary-searches its contributing seq range.

#define T_TILE  32   // t-values per block; 100000 = 3125 * 32 exactly
#define OUT_DIM 128
#define N_WIN   128

__global__ __launch_bounds__(OUT_DIM) void trf_gather_kernel(
    const float* __restrict__ TRFs,      // (nSeq, N_WIN, OUT_DIM)
    const int*   __restrict__ sourceIdx, // (nSeq,) sorted
    int nSeq, int nRealLen,
    float* __restrict__ out)             // (OUT_DIM, nRealLen)
{
    const int d  = threadIdx.x;              // 0..127 -> coalesced reads over d
    const int t0 = blockIdx.x * T_TILE;
    if (t0 >= nRealLen) return;

    // lo = first seq with sourceIdx[seq] >= t0 - (N_WIN-1)
    int lo;
    {
        int target = t0 - (N_WIN - 1);
        int a = 0, b = nSeq;
        while (a < b) { int m = (a + b) >> 1; if (sourceIdx[m] < target) a = m + 1; else b = m; }
        lo = a;
    }
    // hi = first seq with sourceIdx[seq] >= t0 + T_TILE
    int hi;
    {
        int target = t0 + T_TILE;
        int a = lo, b = nSeq;
        while (a < b) { int m = (a + b) >> 1; if (sourceIdx[m] < target) a = m + 1; else b = m; }
        hi = a;
    }

    float acc[T_TILE];
#pragma unroll
    for (int i = 0; i < T_TILE; ++i) acc[i] = 0.f;

    for (int seq = lo; seq < hi; ++seq) {
        // uniform across the wave -> force into SGPR so the k-predicates scalarize
        int s = __builtin_amdgcn_readfirstlane(sourceIdx[seq]);
        const float* row = TRFs + (size_t)seq * (N_WIN * OUT_DIM) + d;
#pragma unroll
        for (int i = 0; i < T_TILE; ++i) {
            int k = (t0 + i) - s;               // wave-uniform predicate:
            if (k >= 0 && k < N_WIN)            // s_cbranch skips whole load
                acc[i] += row[(size_t)k * OUT_DIM];
        }
    }

    // Store: thread d owns out[d, t0 : t0+32] -> 128 B contiguous, 16B-aligned
    float* o = out + (size_t)d * nRealLen + t0;
    const int tmax = nRealLen - t0;
    if (tmax >= T_TILE && (nRealLen & 3) == 0 && (t0 & 3) == 0) {
#pragma unroll
        for (int i = 0; i < T_TILE; i += 4) {
            float4 v = make_float4(acc[i], acc[i + 1], acc[i + 2], acc[i + 3]);
            *reinterpret_cast<float4*>(o + i) = v;
        }
    } else {
        for (int i = 0; i < T_TILE && i < tmax; ++i) o[i] = acc[i];
    }
}

extern "C" void kernel_launch(void* const* d_in, const int* in_sizes, int n_in,
                              void* d_out, int out_size, void* d_ws, size_t ws_size,
                              hipStream_t stream) {
    const float* TRFs      = (const float*)d_in[0];
    const int*   sourceIdx = (const int*)d_in[1];
    // d_in[2] holds nRealLen on device; grid shape needs it host-side, so
    // derive it from out_size (out is OUT_DIM x nRealLen, fp32).
    const int nSeq     = in_sizes[1];
    const int nRealLen = out_size / OUT_DIM;

    const int nBlocks = (nRealLen + T_TILE - 1) / T_TILE;
    trf_gather_kernel<<<nBlocks, OUT_DIM, 0, stream>>>(
        TRFs, sourceIdx, nSeq, nRealLen, (float*)d_out);
}

// Round 2
// 388.166 us; speedup vs baseline: 1.3654x; 1.3654x over previous
//
#include <hip/hip_runtime.h>

// TRF aligner: out[d, t] = sum over seq with s=sourceIdx[seq], 0 <= t-s < N_WIN
// of TRFs[seq, t-s, d]. Gather formulation (no atomics): sourceIdx is sorted,
// so each t-tile binary-searches its contributing seq range.
//
// R2 change vs R1: loads in the seq loop are UNCONDITIONAL (k clamped to
// [0,127], still inside this seq's row) into a temp array, validity applied
// as a select at accumulate time. R1's per-load wave-uniform branches forced
// load->waitcnt(0)->add serialization (VGPR_Count=20!), leaving only ~1 load
// in flight per wave -> 700 GB/s. This keeps 32 loads outstanding per wave.

#define T_TILE  32   // t-values per block; 100000 = 3125 * 32 exactly
#define OUT_DIM 128
#define N_WIN   128

__global__ __launch_bounds__(OUT_DIM, 4) void trf_gather_kernel(
    const float* __restrict__ TRFs,      // (nSeq, N_WIN, OUT_DIM)
    const int*   __restrict__ sourceIdx, // (nSeq,) sorted
    int nSeq, int nRealLen,
    float* __restrict__ out)             // (OUT_DIM, nRealLen)
{
    const int d  = threadIdx.x;              // 0..127 -> coalesced reads over d
    const int t0 = blockIdx.x * T_TILE;
    if (t0 >= nRealLen) return;

    // lo = first seq with sourceIdx[seq] >= t0 - (N_WIN-1)
    int lo;
    {
        int target = t0 - (N_WIN - 1);
        int a = 0, b = nSeq;
        while (a < b) { int m = (a + b) >> 1; if (sourceIdx[m] < target) a = m + 1; else b = m; }
        lo = a;
    }
    // hi = first seq with sourceIdx[seq] >= t0 + T_TILE
    int hi;
    {
        int target = t0 + T_TILE;
        int a = lo, b = nSeq;
        while (a < b) { int m = (a + b) >> 1; if (sourceIdx[m] < target) a = m + 1; else b = m; }
        hi = a;
    }

    float acc[T_TILE];
#pragma unroll
    for (int i = 0; i < T_TILE; ++i) acc[i] = 0.f;

    for (int seq = lo; seq < hi; ++seq) {
        int s = sourceIdx[seq];              // wave-uniform -> scalar load
        const float* row = TRFs + (size_t)seq * (N_WIN * OUT_DIM) + d;
        const int base = t0 - s;             // k = base + i, wave-uniform

        // Phase 1: 32 unconditional, independent loads (clamped k stays
        // inside this seq's row -> always a legal address; clamp dups hit L1)
        float v[T_TILE];
#pragma unroll
        for (int i = 0; i < T_TILE; ++i) {
            int k  = base + i;
            int kc = k < 0 ? 0 : (k > (N_WIN - 1) ? (N_WIN - 1) : k);
            v[i] = row[kc * OUT_DIM];
        }
        // Phase 2: predicated accumulate (select, no branch)
#pragma unroll
        for (int i = 0; i < T_TILE; ++i) {
            int k = base + i;
            acc[i] += (k >= 0 && k < N_WIN) ? v[i] : 0.0f;
        }
    }

    // Store: thread d owns out[d, t0 : t0+32] -> 128 B contiguous, 16B-aligned
    float* o = out + (size_t)d * nRealLen + t0;
    const int tmax = nRealLen - t0;
    if (tmax >= T_TILE && (nRealLen & 3) == 0 && (t0 & 3) == 0) {
#pragma unroll
        for (int i = 0; i < T_TILE; i += 4) {
            float4 v4 = make_float4(acc[i], acc[i + 1], acc[i + 2], acc[i + 3]);
            *reinterpret_cast<float4*>(o + i) = v4;
        }
    } else {
        for (int i = 0; i < T_TILE && i < tmax; ++i) o[i] = acc[i];
    }
}

extern "C" void kernel_launch(void* const* d_in, const int* in_sizes, int n_in,
                              void* d_out, int out_size, void* d_ws, size_t ws_size,
                              hipStream_t stream) {
    const float* TRFs      = (const float*)d_in[0];
    const int*   sourceIdx = (const int*)d_in[1];
    const int    nSeq      = in_sizes[1];
    const int    nRealLen  = out_size / OUT_DIM;   // out is OUT_DIM x nRealLen fp32

    const int nBlocks = (nRealLen + T_TILE - 1) / T_TILE;
    trf_gather_kernel<<<nBlocks, OUT_DIM, 0, stream>>>(
        TRFs, sourceIdx, nSeq, nRealLen, (float*)d_out);
}